// Round 11
// baseline (2497.884 us; speedup 1.0000x reference)
//
#include <hip/hip_runtime.h>

#define HID 512
#define TSTEPS 1000
#define NB 128
#define NIN 5
#define NOUT 2
#define ROWW 516                   // wT2 row: 512 w_rec cols + y0 + y1 + 2 pad
#define ROWB (ROWW * 4)            // 2064 bytes/row
#define DUMMYOFF (HID * ROWB)      // byte offset of the all-zeros row (j=512)
#define BPB 3                      // batches per block (3 x 320 threads)

// Build wT2[j][h]: h<512 -> w_rec[h][j]; h=512/513 -> w_out[h-512][j]; else 0.
// Row j=512 is all zeros (padding target). Re-run every launch (ws re-poisoned).
__global__ void snn_prep(const float* __restrict__ w_rec,
                         const float* __restrict__ w_out,
                         float* __restrict__ wT2) {
  int idx = blockIdx.x * 256 + threadIdx.x;
  const int total = (HID + 1) * ROWW;
  if (idx >= total) return;
  int j = idx / ROWW;
  int h = idx - j * ROWW;
  float v = 0.0f;
  if (j < HID) {
    if (h < HID) v = w_rec[h * HID + j];
    else if (h < HID + NOUT) v = w_out[(h - HID) * HID + j];
  }
  wT2[idx] = v;
}

// 960 threads = 3 independent 5-wave batch engines (round-5 logic per engine).
// Engine: ltid<256 -> units 2t,2t+1; ltid==256 -> readout. One barrier/step
// (block-wide, all 3 engines in lockstep). TLP: 15 waves/CU hides L2 latency.
__global__ __launch_bounds__(320 * BPB) void snn_main(
    const float* __restrict__ x,      // [T][B][5]
    const float* __restrict__ w_in,   // [H][5]
    const float* __restrict__ wT2,    // [513][516]
    float* __restrict__ out)          // [T][B][2]
{
#pragma clang fp contract(off)
  const int tid = threadIdx.x;
  const int half = tid / 320;         // engine 0..2 (wave-aligned: 320 = 5 waves)
  const int ltid = tid - half * 320;
  const int lane = ltid & 63;
  const int wv = ltid >> 6;           // 0..4 within engine
  const int h0 = ltid * 2;            // 512 for the readout lane
  const int batch = blockIdx.x * BPB + half;
  const bool active = batch < NB;
  const int bb = active ? batch : 0;

  __shared__ int __align__(16) s_seg[BPB][2][4][132];  // [engine][buf][wave][ent]
  __shared__ int __align__(16) s_cnt[BPB][2][4];       // padded per-wave counts

  // per-unit input weights
  float wi00 = 0, wi01 = 0, wi02 = 0, wi03 = 0, wi04 = 0;
  float wi10 = 0, wi11 = 0, wi12 = 0, wi13 = 0, wi14 = 0;
  if (ltid < 256) {
    const float* wa = w_in + h0 * NIN;
    wi00 = wa[0]; wi01 = wa[1]; wi02 = wa[2]; wi03 = wa[3]; wi04 = wa[4];
    const float* wb = w_in + (h0 + 1) * NIN;
    wi10 = wb[0]; wi11 = wb[1]; wi12 = wb[2]; wi13 = wb[3]; wi14 = wb[4];
  }

  // state
  float v0 = 0, v1 = 0, c0 = 0, c1 = 0;            // LIF pairs
  float io0 = 0, io1 = 0, vo0 = 0, vo1 = 0;        // LI readout (ltid 256)
  float pend0 = 0, pend1 = 0;

  // x_0
  float xr0, xr1, xr2, xr3, xr4;
  {
    const float* xp = x + (size_t)bb * NIN;
    xr0 = xp[0]; xr1 = xp[1]; xr2 = xp[2]; xr3 = xp[3]; xr4 = xp[4];
  }

  if (ltid < 4) s_cnt[half][0][ltid] = 0;
  __syncthreads();

  const char* wtb = (const char*)wT2 + (size_t)h0 * 4;

  for (int t = 0; t < TSTEPS; ++t) {
    const int rb = t & 1, wbuf = rb ^ 1;

    if (active) {
      // deferred out store (drains during this step's gather)
      if (ltid == 256 && t > 0) {
        float2 po; po.x = pend0; po.y = pend1;
        *(float2*)(out + (size_t)(t - 1) * NB * NOUT + batch * NOUT) = po;
      }

      // prefetch x_{t+1}
      float nx0, nx1, nx2, nx3, nx4;
      {
        const int tn = (t + 1 < TSTEPS) ? t + 1 : t;
        const float* xp = x + ((size_t)tn * NB + bb) * NIN;
        nx0 = xp[0]; nx1 = xp[1]; nx2 = xp[2]; nx3 = xp[3]; nx4 = xp[4];
      }

      // padded per-wave counts of z_{t-1} (single b128 read)
      const int4 c4 = *(const int4*)&s_cnt[half][rb][0];
      const int pc0 = __builtin_amdgcn_readfirstlane(c4.x);
      const int pc1 = __builtin_amdgcn_readfirstlane(c4.y);
      const int pc2 = __builtin_amdgcn_readfirstlane(c4.z);
      const int pc3 = __builtin_amdgcn_readfirstlane(c4.w);
      const int b1 = pc0, b2v = b1 + pc1, b3v = b2v + pc2;
      const int tot = b3v + pc3;
      const int ng = tot >> 2;   // groups of 4 entries

      float racc0 = 0.0f, racc1 = 0.0f;
      if (h0 < HID + NOUT && ng > 0) {
        const char* segbase = (const char*)&s_seg[half][rb][0][0];

#define SEGADDR(GI, AP) { int w_ = 0, bw_ = 0;                         \
        if ((GI) >= b1)  { w_ = 1; bw_ = b1;  }                        \
        if ((GI) >= b2v) { w_ = 2; bw_ = b2v; }                        \
        if ((GI) >= b3v) { w_ = 3; bw_ = b3v; }                        \
        AP = segbase + w_ * 528 + ((GI) - bw_) * 4; }
#define STAGE(JJ, F0, F1, F2, F3, G) { const char* ap_;                \
        SEGADDR((G) * 4, ap_);                                         \
        JJ = *(const int4*)ap_;                                        \
        F0 = *(const float2*)(wtb + JJ.x);                             \
        F1 = *(const float2*)(wtb + JJ.y);                             \
        F2 = *(const float2*)(wtb + JJ.z);                             \
        F3 = *(const float2*)(wtb + JJ.w); }
#define CONSUME(F0, F1, F2, F3) {                                      \
        racc0 = __fadd_rn(racc0, F0.x); racc1 = __fadd_rn(racc1, F0.y);\
        racc0 = __fadd_rn(racc0, F1.x); racc1 = __fadd_rn(racc1, F1.y);\
        racc0 = __fadd_rn(racc0, F2.x); racc1 = __fadd_rn(racc1, F2.y);\
        racc0 = __fadd_rn(racc0, F3.x); racc1 = __fadd_rn(racc1, F3.y); }

        int4 jA, jB;
        float2 a0, a1, a2, a3, q0, q1, q2, q3;
        STAGE(jA, a0, a1, a2, a3, 0);
        int g = 1;
        for (; g + 1 < ng; g += 2) {
          STAGE(jB, q0, q1, q2, q3, g);
          CONSUME(a0, a1, a2, a3);
          STAGE(jA, a0, a1, a2, a3, g + 1);
          CONSUME(q0, q1, q2, q3);
        }
        if (g < ng) {
          STAGE(jB, q0, q1, q2, q3, g);
          CONSUME(a0, a1, a2, a3);
          CONSUME(q0, q1, q2, q3);
        } else {
          CONSUME(a0, a1, a2, a3);
        }
      }

      if (ltid < 256) {
        // input currents (ascending-k chain)
        float a0 = __fmul_rn(xr0, wi00);
        a0 = fmaf(xr1, wi01, a0); a0 = fmaf(xr2, wi02, a0);
        a0 = fmaf(xr3, wi03, a0); a0 = fmaf(xr4, wi04, a0);
        float a1 = __fmul_rn(xr0, wi10);
        a1 = fmaf(xr1, wi11, a1); a1 = fmaf(xr2, wi12, a1);
        a1 = fmaf(xr3, wi13, a1); a1 = fmaf(xr4, wi14, a1);

        const float vd0 = __fadd_rn(v0, __fmul_rn(0.1f, __fsub_rn(c0, v0)));
        const float vd1 = __fadd_rn(v1, __fmul_rn(0.1f, __fsub_rn(c1, v1)));
        const bool s0 = vd0 > 1.0f;
        const bool s1 = vd1 > 1.0f;
        v0 = s0 ? 0.0f : vd0;
        v1 = s1 ? 0.0f : vd1;
        c0 = __fadd_rn(__fmul_rn(0.8f, c0), __fadd_rn(a0, racc0));
        c1 = __fadd_rn(__fmul_rn(0.8f, c1), __fadd_rn(a1, racc1));

        // publish spikes: per-wave segment, ascending j = 2*lane+parity
        const unsigned long long me = __ballot(s0);
        const unsigned long long mo = __ballot(s1);
        const unsigned long long below = (1ull << lane) - 1ull;
        const int cb = __popcll(me & below) + __popcll(mo & below);
        const int cnt = __popcll(me) + __popcll(mo);
        const int pcw = (cnt + 3) & ~3;
        int* seg = &s_seg[half][wbuf][wv][0];
        if (s0) seg[cb] = h0 * ROWB;
        if (s1) seg[cb + (s0 ? 1 : 0)] = (h0 + 1) * ROWB;
        if (lane < pcw - cnt) seg[cnt + lane] = DUMMYOFF;
        if (lane == 0) s_cnt[half][wbuf][wv] = pcw;
      } else if (ltid == 256) {
        // racc = y_t; io_t = 0.8*io_{t-1} + y_t; vo uses OLD io -> out[t]
        io0 = __fadd_rn(__fmul_rn(0.8f, io0), racc0);
        io1 = __fadd_rn(__fmul_rn(0.8f, io1), racc1);
        vo0 = __fadd_rn(vo0, __fmul_rn(0.1f, __fsub_rn(io0, vo0)));
        vo1 = __fadd_rn(vo1, __fmul_rn(0.1f, __fsub_rn(io1, vo1)));
        pend0 = vo0; pend1 = vo1;
      }

      xr0 = nx0; xr1 = nx1; xr2 = nx2; xr3 = nx3; xr4 = nx4;
    }

    __syncthreads();   // single barrier: step t's segments visible for t+1
  }

  if (active && ltid == 256) {
    float2 po; po.x = pend0; po.y = pend1;
    *(float2*)(out + (size_t)(TSTEPS - 1) * NB * NOUT + batch * NOUT) = po;
  }
}

extern "C" void kernel_launch(void* const* d_in, const int* in_sizes, int n_in,
                              void* d_out, int out_size, void* d_ws, size_t ws_size,
                              hipStream_t stream) {
  const float* x     = (const float*)d_in[0];
  const float* w_in  = (const float*)d_in[1];
  const float* w_rec = (const float*)d_in[2];
  const float* w_out = (const float*)d_in[3];
  float* out = (float*)d_out;
  float* wT2 = (float*)d_ws;   // (513*516)*4 ~= 1.06 MB

  const int prep_elems = (HID + 1) * ROWW;
  snn_prep<<<(prep_elems + 255) / 256, 256, 0, stream>>>(w_rec, w_out, wT2);
  const int nblocks = (NB + BPB - 1) / BPB;   // 43
  snn_main<<<nblocks, 320 * BPB, 0, stream>>>(x, w_in, wT2, out);
}